// Round 5
// baseline (582.664 us; speedup 1.0000x reference)
//
#include <hip/hip_runtime.h>
#include <math.h>
#include <stdint.h>

// MFMA fragment types (guide §3, compile-verified on gfx950)
typedef __attribute__((ext_vector_type(8))) short bf16x8;   // 8 bf16 in 4 VGPRs
typedef __attribute__((ext_vector_type(4))) float f32x4;    // 4 fp32 acc

__device__ __forceinline__ unsigned short f2bf(float f) {
    union { float f; unsigned u; } v; v.f = f;
    return (unsigned short)((v.u + 0x7fffu + ((v.u >> 16) & 1u)) >> 16); // RNE
}

// pack two fp32 -> two bf16 in one u32 (round-half-up; inputs finite >=0)
__device__ __forceinline__ unsigned pkbf(float a, float b) {
    union { float f; unsigned u; } x, y; x.f = a; y.f = b;
    return ((y.u + 0x8000u) & 0xffff0000u) | ((x.u + 0x8000u) >> 16);
}

// ---------------- fp32 -> bf16 elementwise (x4 vectorized) ----------------
__global__ void k_convert(const float* __restrict__ in, unsigned short* __restrict__ out, int n4) {
    int i = blockIdx.x * blockDim.x + threadIdx.x;
    if (i >= n4) return;
    float4 f = ((const float4*)in)[i];
    ushort4 o;
    o.x = f2bf(f.x); o.y = f2bf(f.y); o.z = f2bf(f.z); o.w = f2bf(f.w);
    ((ushort4*)out)[i] = o;
}

// ---------------- fp32 [R][C] -> bf16 [C][R] (tiled transpose) ----------------
__global__ void k_transpose(const float* __restrict__ in, unsigned short* __restrict__ out, int R, int C) {
    __shared__ float tile[32][33];
    int c0 = blockIdx.x * 32, r0 = blockIdx.y * 32;
    int tx = threadIdx.x, ty = threadIdx.y; // block (32,8)
#pragma unroll
    for (int i = 0; i < 4; ++i)
        tile[ty + i * 8][tx] = in[(size_t)(r0 + ty + i * 8) * C + c0 + tx];
    __syncthreads();
#pragma unroll
    for (int i = 0; i < 4; ++i)
        out[(size_t)(c0 + ty + i * 8) * R + r0 + tx] = f2bf(tile[tx][ty + i * 8]);
}

// ---------------- 128x128 bf16 MFMA GEMM core ----------------
#define LDT 40

__device__ __forceinline__ void gemm_core(
    const unsigned short* __restrict__ A, const unsigned short* __restrict__ Bt,
    int K, unsigned short* As, unsigned short* Bs, f32x4 (&acc)[4][4])
{
    const int tid  = threadIdx.x;
    const int lane = tid & 63;
    const int w    = tid >> 6;
    const int wm   = (w >> 1) * 64, wn = (w & 1) * 64;
    const int l15  = lane & 15, quad = lane >> 4;
    const int m0 = blockIdx.x * 128, n0 = blockIdx.y * 128;

    const f32x4 zero = {0.f, 0.f, 0.f, 0.f};
#pragma unroll
    for (int i = 0; i < 4; ++i)
#pragma unroll
        for (int j = 0; j < 4; ++j) acc[i][j] = zero;

    const int r0 = tid >> 2, p8 = (tid & 3) * 8;
    const unsigned short* Ag0 = A  + (size_t)(m0 + r0) * K + p8;
    const unsigned short* Ag1 = A  + (size_t)(m0 + r0 + 64) * K + p8;
    const unsigned short* Bg0 = Bt + (size_t)(n0 + r0) * K + p8;
    const unsigned short* Bg1 = Bt + (size_t)(n0 + r0 + 64) * K + p8;

    int4 a0 = *(const int4*)Ag0;
    int4 a1 = *(const int4*)Ag1;
    int4 b0 = *(const int4*)Bg0;
    int4 b1 = *(const int4*)Bg1;

    const int nk = K >> 5;
    for (int kt = 0; kt < nk; ++kt) {
        __syncthreads();
        *(int4*)&As[r0 * LDT + p8]        = a0;
        *(int4*)&As[(r0 + 64) * LDT + p8] = a1;
        *(int4*)&Bs[r0 * LDT + p8]        = b0;
        *(int4*)&Bs[(r0 + 64) * LDT + p8] = b1;
        __syncthreads();
        if (kt + 1 < nk) {
            int koff = (kt + 1) * 32;
            a0 = *(const int4*)(Ag0 + koff);
            a1 = *(const int4*)(Ag1 + koff);
            b0 = *(const int4*)(Bg0 + koff);
            b1 = *(const int4*)(Bg1 + koff);
        }
        bf16x8 af[4], bfr[4];
#pragma unroll
        for (int mi = 0; mi < 4; ++mi)
            af[mi] = *(const bf16x8*)&As[(wm + mi * 16 + l15) * LDT + quad * 8];
#pragma unroll
        for (int nj = 0; nj < 4; ++nj)
            bfr[nj] = *(const bf16x8*)&Bs[(wn + nj * 16 + l15) * LDT + quad * 8];
#pragma unroll
        for (int mi = 0; mi < 4; ++mi)
#pragma unroll
            for (int nj = 0; nj < 4; ++nj)
                acc[mi][nj] = __builtin_amdgcn_mfma_f32_16x16x32_bf16(af[mi], bfr[nj], acc[mi][nj], 0, 0, 0);
    }
}

// QKV GEMM epilogue scatters into FRAGMENT-ORDER buffers so every attention
// global load is one coalesced 1024B block (base + lane*16B):
//  QL[bh][qi][m][h][lane][8]  : lane(l15,quad) holds Q[qi*32+16m+l15][32h+8quad+j]
//  KL[bh][t ][i][h][lane][8]  : lane holds K[64t+16i+l15][32h+8quad+j]
//  VL[bh][t ][dj][h][lane][8] : lane holds V[64t+32h+8quad+j][16dj+l15]
// Q pre-scaled by (1/8)*log2(e): softmax runs in exp2 domain.
__global__ __launch_bounds__(256) void k_gemm_qkv(
    const unsigned short* __restrict__ A, const unsigned short* __restrict__ Bt,
    const float* __restrict__ bias,
    unsigned short* __restrict__ QL, unsigned short* __restrict__ KL,
    unsigned short* __restrict__ VL)
{
    __shared__ __align__(16) unsigned short As[128 * LDT];
    __shared__ __align__(16) unsigned short Bs[128 * LDT];
    f32x4 acc[4][4];
    gemm_core(A, Bt, 768, As, Bs, acc);

    const int tid = threadIdx.x, lane = tid & 63, w = tid >> 6;
    const int wm = (w >> 1) * 64, wn = (w & 1) * 64;
    const int l15 = lane & 15, quad = lane >> 4;
    const int m0 = blockIdx.x * 128, n0 = blockIdx.y * 128;
    const float cscale = 0.18033688011f;  // (1/8) * log2(e)
#pragma unroll
    for (int nj = 0; nj < 4; ++nj) {
        int cg = n0 + wn + nj * 16 + l15;        // column in [0,2304)
        float bv = bias[cg];
        int which = cg / 768;                    // 0=q 1=k 2=v
        int rem = cg - which * 768;
        int hd = rem >> 6, d = rem & 63;
        float sc = (which == 0) ? cscale : 1.0f;
#pragma unroll
        for (int mi = 0; mi < 4; ++mi) {
#pragma unroll
            for (int r = 0; r < 4; ++r) {
                int rg = m0 + wm + mi * 16 + quad * 4 + r;   // row in [0,8192)
                int b = rg >> 12, tk = rg & 4095;
                int bh = b * 12 + hd;
                unsigned short ob = f2bf((acc[mi][nj][r] + bv) * sc);
                if (which == 0) {
                    // Q: qi=tk>>5, m=(tk>>4)&1, l=tk&15; h=d>>5, qd=(d>>3)&3, j=d&7
                    size_t idx = ((((size_t)bh * 128 + (tk >> 5)) * 2 + ((tk >> 4) & 1)) * 2 + (d >> 5)) * 512
                               + ((d >> 3) & 3) * 128 + (tk & 15) * 8 + (d & 7);
                    QL[idx] = ob;
                } else if (which == 1) {
                    // K: t=tk>>6, i=(tk>>4)&3, l=tk&15; h=d>>5, qd=(d>>3)&3, j=d&7
                    size_t idx = ((((size_t)bh * 64 + (tk >> 6)) * 4 + ((tk >> 4) & 3)) * 2 + (d >> 5)) * 512
                               + ((d >> 3) & 3) * 128 + (tk & 15) * 8 + (d & 7);
                    KL[idx] = ob;
                } else {
                    // V: t=tk>>6, wi=tk&63: h=wi>>5, qv=(wi>>3)&3, j=wi&7; dj=d>>4, l=d&15
                    int wi = tk & 63;
                    size_t idx = ((((size_t)bh * 64 + (tk >> 6)) * 4 + (d >> 4)) * 2 + (wi >> 5)) * 512
                               + ((wi >> 3) & 3) * 128 + (d & 15) * 8 + (wi & 7);
                    VL[idx] = ob;
                }
            }
        }
    }
}

// Proj GEMM: A = y bf16 [8192][768], Bt = WprojT [768][768], out fp32 + bias
__global__ __launch_bounds__(256) void k_gemm_proj(
    const unsigned short* __restrict__ A, const unsigned short* __restrict__ Bt,
    const float* __restrict__ bias, float* __restrict__ out)
{
    __shared__ __align__(16) unsigned short As[128 * LDT];
    __shared__ __align__(16) unsigned short Bs[128 * LDT];
    f32x4 acc[4][4];
    gemm_core(A, Bt, 768, As, Bs, acc);

    const int tid = threadIdx.x, lane = tid & 63, w = tid >> 6;
    const int wm = (w >> 1) * 64, wn = (w & 1) * 64;
    const int l15 = lane & 15, quad = lane >> 4;
    const int m0 = blockIdx.x * 128, n0 = blockIdx.y * 128;
#pragma unroll
    for (int nj = 0; nj < 4; ++nj) {
        int cg = n0 + wn + nj * 16 + l15;
        float bv = bias[cg];
#pragma unroll
        for (int mi = 0; mi < 4; ++mi)
#pragma unroll
            for (int r = 0; r < 4; ++r) {
                int rg = m0 + wm + mi * 16 + quad * 4 + r;
                out[(size_t)rg * 768 + cg] = acc[mi][nj][r] + bv;
            }
    }
}

// ---------------- Flash attention, causal, split-K, XCD-local ----------------
// grid id = qidx*24 + bh => XCD = id%8 = bh%8: 3 heads/XCD, K+V set 3MB < L2.
// Block = 4 waves over the SAME 32 q-rows; wave c handles key tiles
// [c*nkt/4,(c+1)*nkt/4). No-max exp2 softmax => partials additive; combined
// via LDS at block end. All Q/K/V loads are coalesced 1024B fragment blocks.
#define LDP 68   // P row stride in shorts

__global__ __launch_bounds__(256, 4) void k_attn(
    const unsigned short* __restrict__ QL, const unsigned short* __restrict__ KL,
    const unsigned short* __restrict__ VL, unsigned short* __restrict__ Y)
{
    // P regions (4 x 32 x LDP shorts = 17408B) and combine buffer (30720B):
    // disjoint lifetimes -> union.
    __shared__ __align__(16) char smem[30720];
    unsigned short* Ps = (unsigned short*)smem;
    float* Cb = (float*)smem;

    const int tid = threadIdx.x, lane = tid & 63, w = tid >> 6;
    const int l15 = lane & 15, quad = lane >> 4;
    const int id = blockIdx.x;
    const int bh = id % 24;
    const int qi = 127 - id / 24;                     // longest first
    const int q0 = qi * 32;
    const int nkt = qi / 2 + 1;                       // 64-key tiles (causal)
    const int lo = (nkt * w) >> 2, hi = (nkt * (w + 1)) >> 2;
    unsigned short* Pw = Ps + w * 32 * LDP;

    // fragment-chunk bases (each chunk = 512 shorts = 1024B, lane offset *8)
    const unsigned short* Qb = QL + (((size_t)bh * 128 + qi) * 4) * 512 + lane * 8;
    const unsigned short* Kb = KL + ((size_t)bh * 64) * 8 * 512 + lane * 8;
    const unsigned short* Vb = VL + ((size_t)bh * 64) * 8 * 512 + lane * 8;

    // Q^T B-fragments (chunk layout matches B-frag exactly)
    bf16x8 qt[2][2];
#pragma unroll
    for (int m = 0; m < 2; ++m)
#pragma unroll
        for (int h = 0; h < 2; ++h)
            qt[m][h] = *(const bf16x8*)(Qb + (m * 2 + h) * 512);

    const f32x4 zero = {0.f, 0.f, 0.f, 0.f};
    f32x4 O[2][4], lac[2];
#pragma unroll
    for (int m = 0; m < 2; ++m) {
        lac[m] = zero;
#pragma unroll
        for (int dj = 0; dj < 4; ++dj) O[m][dj] = zero;
    }

    const short ONE = (short)0x3F80;  // bf16 1.0
    const bf16x8 onesf = {ONE, ONE, ONE, ONE, ONE, ONE, ONE, ONE};

    if (lo < hi) {
        // K A-fragments for first tile
        bf16x8 ka[4][2];
#pragma unroll
        for (int i = 0; i < 4; ++i)
#pragma unroll
            for (int h = 0; h < 2; ++h)
                ka[i][h] = *(const bf16x8*)(Kb + ((size_t)lo * 8 + i * 2 + h) * 512);

        for (int kt = lo; kt < hi; ++kt) {
            const int kbase = kt * 64;

            // ---- S^T = K Q^T : lane holds (key = i*16+quad*4+r, qrow = m*16+l15)
            f32x4 st[2][4];
#pragma unroll
            for (int i = 0; i < 4; ++i)
#pragma unroll
                for (int m = 0; m < 2; ++m) {
                    f32x4 z = __builtin_amdgcn_mfma_f32_16x16x32_bf16(ka[i][0], qt[m][0], zero, 0, 0, 0);
                    st[m][i] = __builtin_amdgcn_mfma_f32_16x16x32_bf16(ka[i][1], qt[m][1], z, 0, 0, 0);
                }

            // ---- V B-fragments for this tile (coalesced chunks; early issue)
            bf16x8 vf[4][2];
#pragma unroll
            for (int dj = 0; dj < 4; ++dj)
#pragma unroll
                for (int h = 0; h < 2; ++h)
                    vf[dj][h] = *(const bf16x8*)(Vb + ((size_t)kt * 8 + dj * 2 + h) * 512);

            // ---- K prefetch for next tile
            if (kt + 1 < hi) {
#pragma unroll
                for (int i = 0; i < 4; ++i)
#pragma unroll
                    for (int h = 0; h < 2; ++h)
                        ka[i][h] = *(const bf16x8*)(Kb + ((size_t)(kt + 1) * 8 + i * 2 + h) * 512);
            }

            // ---- causal mask on diagonal tile (always owned by wave 3)
            if (kt == nkt - 1) {
#pragma unroll
                for (int m = 0; m < 2; ++m)
#pragma unroll
                    for (int i = 0; i < 4; ++i)
#pragma unroll
                        for (int r = 0; r < 4; ++r)
                            if (kbase + i * 16 + quad * 4 + r > q0 + m * 16 + l15)
                                st[m][i][r] = -INFINITY;
            }

            // ---- p = exp2(s) (no max; logits sigma~1.4, fp32-safe), pack b64
#pragma unroll
            for (int m = 0; m < 2; ++m)
#pragma unroll
                for (int i = 0; i < 4; ++i) {
                    float p0 = exp2f(fminf(st[m][i][0], 80.f));
                    float p1 = exp2f(fminf(st[m][i][1], 80.f));
                    float p2 = exp2f(fminf(st[m][i][2], 80.f));
                    float p3 = exp2f(fminf(st[m][i][3], 80.f));
                    uint2 pk; pk.x = pkbf(p0, p1); pk.y = pkbf(p2, p3);
                    *(uint2*)&Pw[(size_t)(m * 16 + l15) * LDP + i * 16 + quad * 4] = pk;
                }

            // ---- read P back as A-frags (same-wave LDS RAW)
            bf16x8 pa[2][2];
#pragma unroll
            for (int m = 0; m < 2; ++m) {
                pa[m][0] = *(const bf16x8*)&Pw[(size_t)(m * 16 + l15) * LDP + quad * 8];
                pa[m][1] = *(const bf16x8*)&Pw[(size_t)(m * 16 + l15) * LDP + 32 + quad * 8];
            }

            // ---- l += P @ ones ; O += P V
#pragma unroll
            for (int m = 0; m < 2; ++m) {
                f32x4 z = __builtin_amdgcn_mfma_f32_16x16x32_bf16(pa[m][0], onesf, lac[m], 0, 0, 0);
                lac[m] = __builtin_amdgcn_mfma_f32_16x16x32_bf16(pa[m][1], onesf, z, 0, 0, 0);
            }
#pragma unroll
            for (int dj = 0; dj < 4; ++dj)
#pragma unroll
                for (int m = 0; m < 2; ++m) {
                    f32x4 z = __builtin_amdgcn_mfma_f32_16x16x32_bf16(pa[m][0], vf[dj][0], O[m][dj], 0, 0, 0);
                    O[m][dj] = __builtin_amdgcn_mfma_f32_16x16x32_bf16(pa[m][1], vf[dj][1], z, 0, 0, 0);
                }
        }
    }

    // ---- combine the 4 partial (O,l) via LDS (additive: no max was used)
    __syncthreads();   // all waves done with their P regions
    if (w > 0) {
        float* Ow = Cb + (w - 1) * 2560;
#pragma unroll
        for (int m = 0; m < 2; ++m) {
#pragma unroll
            for (int dj = 0; dj < 4; ++dj)
                *(f32x4*)&Ow[(m * 4 + dj) * 256 + lane * 4] = O[m][dj];
            *(f32x4*)&Ow[2048 + m * 256 + lane * 4] = lac[m];
        }
    }
    __syncthreads();
    if (w == 0) {
#pragma unroll
        for (int c = 0; c < 3; ++c) {
            const float* Ow = Cb + c * 2560;
#pragma unroll
            for (int m = 0; m < 2; ++m) {
#pragma unroll
                for (int dj = 0; dj < 4; ++dj)
                    O[m][dj] += *(const f32x4*)&Ow[(m * 4 + dj) * 256 + lane * 4];
                lac[m] += *(const f32x4*)&Ow[2048 + m * 256 + lane * 4];
            }
        }
        // epilogue: O / l -> Y [b][t][h*64+d] bf16
        const int b = bh / 12, hd = bh % 12;
#pragma unroll
        for (int m = 0; m < 2; ++m)
#pragma unroll
            for (int r = 0; r < 4; ++r) {
                float inv = 1.0f / lac[m][r];
                int t = q0 + 16 * m + quad * 4 + r;
                size_t base = ((size_t)(b * 4096 + t)) * 768 + hd * 64;
#pragma unroll
                for (int dj = 0; dj < 4; ++dj)
                    Y[base + dj * 16 + l15] = f2bf(O[m][dj][r] * inv);
            }
    }
}

// ---------------- launch ----------------
extern "C" void kernel_launch(void* const* d_in, const int* in_sizes, int n_in,
                              void* d_out, int out_size, void* d_ws, size_t ws_size,
                              hipStream_t stream) {
    (void)in_sizes; (void)n_in; (void)out_size; (void)ws_size;
    const float* x     = (const float*)d_in[0];
    const float* Wqkv  = (const float*)d_in[1];
    const float* bqkv  = (const float*)d_in[2];
    const float* Wproj = (const float*)d_in[3];
    const float* bproj = (const float*)d_in[4];
    float* out = (float*)d_out;

    char* ws = (char*)d_ws;
    size_t off = 0;
    auto alloc = [&](size_t bytes) -> void* {
        void* p = ws + off;
        off += (bytes + 255) & ~(size_t)255;
        return p;
    };
    unsigned short* xb     = (unsigned short*)alloc((size_t)8192 * 768 * 2);
    unsigned short* WqkvT  = (unsigned short*)alloc((size_t)2304 * 768 * 2);
    unsigned short* WprojT = (unsigned short*)alloc((size_t)768 * 768 * 2);
    unsigned short* QLb    = (unsigned short*)alloc((size_t)24 * 4096 * 64 * 2);
    unsigned short* KLb    = (unsigned short*)alloc((size_t)24 * 4096 * 64 * 2);
    unsigned short* VLb    = (unsigned short*)alloc((size_t)24 * 4096 * 64 * 2);
    unsigned short* Yb     = (unsigned short*)alloc((size_t)8192 * 768 * 2);

    k_convert<<<6144, 256, 0, stream>>>(x, xb, 8192 * 768 / 4);
    dim3 tb(32, 8);
    k_transpose<<<dim3(72, 24), tb, 0, stream>>>(Wqkv, WqkvT, 768, 2304);
    k_transpose<<<dim3(24, 24), tb, 0, stream>>>(Wproj, WprojT, 768, 768);
    k_gemm_qkv<<<dim3(64, 18), 256, 0, stream>>>(xb, WqkvT, bqkv, QLb, KLb, VLb);
    k_attn<<<dim3(3072), 256, 0, stream>>>(QLb, KLb, VLb, Yb);
    k_gemm_proj<<<dim3(64, 6), 256, 0, stream>>>(Yb, WprojT, bproj, out);
}

// Round 6
// 271.777 us; speedup vs baseline: 2.1439x; 2.1439x over previous
//
#include <hip/hip_runtime.h>
#include <math.h>
#include <stdint.h>

// MFMA fragment types (guide §3, compile-verified on gfx950)
typedef __attribute__((ext_vector_type(8))) short bf16x8;   // 8 bf16 in 4 VGPRs
typedef __attribute__((ext_vector_type(4))) float f32x4;    // 4 fp32 acc

__device__ __forceinline__ unsigned short f2bf(float f) {
    union { float f; unsigned u; } v; v.f = f;
    return (unsigned short)((v.u + 0x7fffu + ((v.u >> 16) & 1u)) >> 16); // RNE
}

// pack two fp32 -> two bf16 in one u32 (round-half-up; inputs finite >=0)
__device__ __forceinline__ unsigned pkbf(float a, float b) {
    union { float f; unsigned u; } x, y; x.f = a; y.f = b;
    return ((y.u + 0x8000u) & 0xffff0000u) | ((x.u + 0x8000u) >> 16);
}

// ---------------- fp32 -> bf16 elementwise (x4 vectorized) ----------------
__global__ void k_convert(const float* __restrict__ in, unsigned short* __restrict__ out, int n4) {
    int i = blockIdx.x * blockDim.x + threadIdx.x;
    if (i >= n4) return;
    float4 f = ((const float4*)in)[i];
    ushort4 o;
    o.x = f2bf(f.x); o.y = f2bf(f.y); o.z = f2bf(f.z); o.w = f2bf(f.w);
    ((ushort4*)out)[i] = o;
}

// ---------------- fp32 [R][C] -> bf16 [C][R] (tiled transpose) ----------------
__global__ void k_transpose(const float* __restrict__ in, unsigned short* __restrict__ out, int R, int C) {
    __shared__ float tile[32][33];
    int c0 = blockIdx.x * 32, r0 = blockIdx.y * 32;
    int tx = threadIdx.x, ty = threadIdx.y; // block (32,8)
#pragma unroll
    for (int i = 0; i < 4; ++i)
        tile[ty + i * 8][tx] = in[(size_t)(r0 + ty + i * 8) * C + c0 + tx];
    __syncthreads();
#pragma unroll
    for (int i = 0; i < 4; ++i)
        out[(size_t)(c0 + ty + i * 8) * R + r0 + tx] = f2bf(tile[tx][ty + i * 8]);
}

// ---------------- 128x128 bf16 MFMA GEMM core ----------------
#define LDT 40

__device__ __forceinline__ void gemm_core(
    const unsigned short* __restrict__ A, const unsigned short* __restrict__ Bt,
    int K, unsigned short* As, unsigned short* Bs, f32x4 (&acc)[4][4])
{
    const int tid  = threadIdx.x;
    const int lane = tid & 63;
    const int w    = tid >> 6;
    const int wm   = (w >> 1) * 64, wn = (w & 1) * 64;
    const int l15  = lane & 15, quad = lane >> 4;
    const int m0 = blockIdx.x * 128, n0 = blockIdx.y * 128;

    const f32x4 zero = {0.f, 0.f, 0.f, 0.f};
#pragma unroll
    for (int i = 0; i < 4; ++i)
#pragma unroll
        for (int j = 0; j < 4; ++j) acc[i][j] = zero;

    const int r0 = tid >> 2, p8 = (tid & 3) * 8;
    const unsigned short* Ag0 = A  + (size_t)(m0 + r0) * K + p8;
    const unsigned short* Ag1 = A  + (size_t)(m0 + r0 + 64) * K + p8;
    const unsigned short* Bg0 = Bt + (size_t)(n0 + r0) * K + p8;
    const unsigned short* Bg1 = Bt + (size_t)(n0 + r0 + 64) * K + p8;

    int4 a0 = *(const int4*)Ag0;
    int4 a1 = *(const int4*)Ag1;
    int4 b0 = *(const int4*)Bg0;
    int4 b1 = *(const int4*)Bg1;

    const int nk = K >> 5;
    for (int kt = 0; kt < nk; ++kt) {
        __syncthreads();
        *(int4*)&As[r0 * LDT + p8]        = a0;
        *(int4*)&As[(r0 + 64) * LDT + p8] = a1;
        *(int4*)&Bs[r0 * LDT + p8]        = b0;
        *(int4*)&Bs[(r0 + 64) * LDT + p8] = b1;
        __syncthreads();
        if (kt + 1 < nk) {
            int koff = (kt + 1) * 32;
            a0 = *(const int4*)(Ag0 + koff);
            a1 = *(const int4*)(Ag1 + koff);
            b0 = *(const int4*)(Bg0 + koff);
            b1 = *(const int4*)(Bg1 + koff);
        }
        bf16x8 af[4], bfr[4];
#pragma unroll
        for (int mi = 0; mi < 4; ++mi)
            af[mi] = *(const bf16x8*)&As[(wm + mi * 16 + l15) * LDT + quad * 8];
#pragma unroll
        for (int nj = 0; nj < 4; ++nj)
            bfr[nj] = *(const bf16x8*)&Bs[(wn + nj * 16 + l15) * LDT + quad * 8];
#pragma unroll
        for (int mi = 0; mi < 4; ++mi)
#pragma unroll
            for (int nj = 0; nj < 4; ++nj)
                acc[mi][nj] = __builtin_amdgcn_mfma_f32_16x16x32_bf16(af[mi], bfr[nj], acc[mi][nj], 0, 0, 0);
    }
}

// QKV GEMM epilogue scatters into FRAGMENT-ORDER buffers so every attention
// global load is one coalesced 1024B block (base + lane*16B):
//  QL[bh][qi][m][h][lane][8]  : lane(l15,quad) holds Q[qi*32+16m+l15][32h+8quad+j]
//  KL[bh][t ][i][h][lane][8]  : lane holds K[64t+16i+l15][32h+8quad+j]
//  VL[bh][t ][dj][h][lane][8] : lane holds V[64t+32h+8quad+j][16dj+l15]
// Q pre-scaled by (1/8)*log2(e): softmax runs in exp2 domain.
__global__ __launch_bounds__(256) void k_gemm_qkv(
    const unsigned short* __restrict__ A, const unsigned short* __restrict__ Bt,
    const float* __restrict__ bias,
    unsigned short* __restrict__ QL, unsigned short* __restrict__ KL,
    unsigned short* __restrict__ VL)
{
    __shared__ __align__(16) unsigned short As[128 * LDT];
    __shared__ __align__(16) unsigned short Bs[128 * LDT];
    f32x4 acc[4][4];
    gemm_core(A, Bt, 768, As, Bs, acc);

    const int tid = threadIdx.x, lane = tid & 63, w = tid >> 6;
    const int wm = (w >> 1) * 64, wn = (w & 1) * 64;
    const int l15 = lane & 15, quad = lane >> 4;
    const int m0 = blockIdx.x * 128, n0 = blockIdx.y * 128;
    const float cscale = 0.18033688011f;  // (1/8) * log2(e)
#pragma unroll
    for (int nj = 0; nj < 4; ++nj) {
        int cg = n0 + wn + nj * 16 + l15;        // column in [0,2304)
        float bv = bias[cg];
        int which = cg / 768;                    // 0=q 1=k 2=v
        int rem = cg - which * 768;
        int hd = rem >> 6, d = rem & 63;
        float sc = (which == 0) ? cscale : 1.0f;
#pragma unroll
        for (int mi = 0; mi < 4; ++mi) {
#pragma unroll
            for (int r = 0; r < 4; ++r) {
                int rg = m0 + wm + mi * 16 + quad * 4 + r;   // row in [0,8192)
                int b = rg >> 12, tk = rg & 4095;
                int bh = b * 12 + hd;
                unsigned short ob = f2bf((acc[mi][nj][r] + bv) * sc);
                if (which == 0) {
                    // Q: qi=tk>>5, m=(tk>>4)&1, l=tk&15; h=d>>5, qd=(d>>3)&3, j=d&7
                    size_t idx = ((((size_t)bh * 128 + (tk >> 5)) * 2 + ((tk >> 4) & 1)) * 2 + (d >> 5)) * 512
                               + ((d >> 3) & 3) * 128 + (tk & 15) * 8 + (d & 7);
                    QL[idx] = ob;
                } else if (which == 1) {
                    // K: t=tk>>6, i=(tk>>4)&3, l=tk&15; h=d>>5, qd=(d>>3)&3, j=d&7
                    size_t idx = ((((size_t)bh * 64 + (tk >> 6)) * 4 + ((tk >> 4) & 3)) * 2 + (d >> 5)) * 512
                               + ((d >> 3) & 3) * 128 + (tk & 15) * 8 + (d & 7);
                    KL[idx] = ob;
                } else {
                    // V: t=tk>>6, wi=tk&63: h=wi>>5, qv=(wi>>3)&3, j=wi&7; dj=d>>4, l=d&15
                    int wi = tk & 63;
                    size_t idx = ((((size_t)bh * 64 + (tk >> 6)) * 4 + (d >> 4)) * 2 + (wi >> 5)) * 512
                               + ((wi >> 3) & 3) * 128 + (d & 15) * 8 + (wi & 7);
                    VL[idx] = ob;
                }
            }
        }
    }
}

// Proj GEMM: A = y bf16 [8192][768], Bt = WprojT [768][768], out fp32 + bias
__global__ __launch_bounds__(256) void k_gemm_proj(
    const unsigned short* __restrict__ A, const unsigned short* __restrict__ Bt,
    const float* __restrict__ bias, float* __restrict__ out)
{
    __shared__ __align__(16) unsigned short As[128 * LDT];
    __shared__ __align__(16) unsigned short Bs[128 * LDT];
    f32x4 acc[4][4];
    gemm_core(A, Bt, 768, As, Bs, acc);

    const int tid = threadIdx.x, lane = tid & 63, w = tid >> 6;
    const int wm = (w >> 1) * 64, wn = (w & 1) * 64;
    const int l15 = lane & 15, quad = lane >> 4;
    const int m0 = blockIdx.x * 128, n0 = blockIdx.y * 128;
#pragma unroll
    for (int nj = 0; nj < 4; ++nj) {
        int cg = n0 + wn + nj * 16 + l15;
        float bv = bias[cg];
#pragma unroll
        for (int mi = 0; mi < 4; ++mi)
#pragma unroll
            for (int r = 0; r < 4; ++r) {
                int rg = m0 + wm + mi * 16 + quad * 4 + r;
                out[(size_t)rg * 768 + cg] = acc[mi][nj][r] + bv;
            }
    }
}

// ---------------- Flash attention, causal, split-K, XCD-local ----------------
// grid id = qidx*24 + bh => XCD = id%8 = bh%8: 3 heads/XCD, K+V set 3MB < L2.
// Block = 4 waves over the SAME 32 q-rows; wave c handles key tiles
// [c*nkt/4,(c+1)*nkt/4). No-max exp2 softmax => partials additive; combined
// via LDS at block end. All Q/K/V loads are coalesced 1024B fragment blocks.
// NOTE: no min-waves launch bound — R5's (256,4) forced VGPR<=64 and spilled
// ~1.9GB of scratch to HBM (WRITE_SIZE 12MB -> 1GB). Default lets the
// allocator pick ~112 VGPR, zero spills (R4-proven).
#define LDP 68   // P row stride in shorts

__global__ __launch_bounds__(256) void k_attn(
    const unsigned short* __restrict__ QL, const unsigned short* __restrict__ KL,
    const unsigned short* __restrict__ VL, unsigned short* __restrict__ Y)
{
    // P regions (4 x 32 x LDP shorts = 17408B) and combine buffer (30720B):
    // disjoint lifetimes -> union.
    __shared__ __align__(16) char smem[30720];
    unsigned short* Ps = (unsigned short*)smem;
    float* Cb = (float*)smem;

    const int tid = threadIdx.x, lane = tid & 63, w = tid >> 6;
    const int l15 = lane & 15, quad = lane >> 4;
    const int id = blockIdx.x;
    const int bh = id % 24;
    const int qi = 127 - id / 24;                     // longest first
    const int q0 = qi * 32;
    const int nkt = qi / 2 + 1;                       // 64-key tiles (causal)
    const int lo = (nkt * w) >> 2, hi = (nkt * (w + 1)) >> 2;
    unsigned short* Pw = Ps + w * 32 * LDP;

    // fragment-chunk bases (each chunk = 512 shorts = 1024B, lane offset *8)
    const unsigned short* Qb = QL + (((size_t)bh * 128 + qi) * 4) * 512 + lane * 8;
    const unsigned short* Kb = KL + ((size_t)bh * 64) * 8 * 512 + lane * 8;
    const unsigned short* Vb = VL + ((size_t)bh * 64) * 8 * 512 + lane * 8;

    // Q^T B-fragments (chunk layout matches B-frag exactly)
    bf16x8 qt[2][2];
#pragma unroll
    for (int m = 0; m < 2; ++m)
#pragma unroll
        for (int h = 0; h < 2; ++h)
            qt[m][h] = *(const bf16x8*)(Qb + (m * 2 + h) * 512);

    const f32x4 zero = {0.f, 0.f, 0.f, 0.f};
    f32x4 O[2][4], lac[2];
#pragma unroll
    for (int m = 0; m < 2; ++m) {
        lac[m] = zero;
#pragma unroll
        for (int dj = 0; dj < 4; ++dj) O[m][dj] = zero;
    }

    const short ONE = (short)0x3F80;  // bf16 1.0
    const bf16x8 onesf = {ONE, ONE, ONE, ONE, ONE, ONE, ONE, ONE};

    if (lo < hi) {
        // K A-fragments for first tile
        bf16x8 ka[4][2];
#pragma unroll
        for (int i = 0; i < 4; ++i)
#pragma unroll
            for (int h = 0; h < 2; ++h)
                ka[i][h] = *(const bf16x8*)(Kb + ((size_t)lo * 8 + i * 2 + h) * 512);

        for (int kt = lo; kt < hi; ++kt) {
            const int kbase = kt * 64;

            // ---- S^T = K Q^T : lane holds (key = i*16+quad*4+r, qrow = m*16+l15)
            f32x4 st[2][4];
#pragma unroll
            for (int i = 0; i < 4; ++i)
#pragma unroll
                for (int m = 0; m < 2; ++m) {
                    f32x4 z = __builtin_amdgcn_mfma_f32_16x16x32_bf16(ka[i][0], qt[m][0], zero, 0, 0, 0);
                    st[m][i] = __builtin_amdgcn_mfma_f32_16x16x32_bf16(ka[i][1], qt[m][1], z, 0, 0, 0);
                }

            // ---- V B-fragments for this tile (coalesced chunks; early issue)
            bf16x8 vf[4][2];
#pragma unroll
            for (int dj = 0; dj < 4; ++dj)
#pragma unroll
                for (int h = 0; h < 2; ++h)
                    vf[dj][h] = *(const bf16x8*)(Vb + ((size_t)kt * 8 + dj * 2 + h) * 512);

            // ---- K prefetch for next tile
            if (kt + 1 < hi) {
#pragma unroll
                for (int i = 0; i < 4; ++i)
#pragma unroll
                    for (int h = 0; h < 2; ++h)
                        ka[i][h] = *(const bf16x8*)(Kb + ((size_t)(kt + 1) * 8 + i * 2 + h) * 512);
            }

            // ---- causal mask on diagonal tile (always owned by wave 3)
            if (kt == nkt - 1) {
#pragma unroll
                for (int m = 0; m < 2; ++m)
#pragma unroll
                    for (int i = 0; i < 4; ++i)
#pragma unroll
                        for (int r = 0; r < 4; ++r)
                            if (kbase + i * 16 + quad * 4 + r > q0 + m * 16 + l15)
                                st[m][i][r] = -INFINITY;
            }

            // ---- p = exp2(s) (no max; logits sigma~1.4, fp32-safe), pack b64
#pragma unroll
            for (int m = 0; m < 2; ++m)
#pragma unroll
                for (int i = 0; i < 4; ++i) {
                    float p0 = exp2f(fminf(st[m][i][0], 80.f));
                    float p1 = exp2f(fminf(st[m][i][1], 80.f));
                    float p2 = exp2f(fminf(st[m][i][2], 80.f));
                    float p3 = exp2f(fminf(st[m][i][3], 80.f));
                    uint2 pk; pk.x = pkbf(p0, p1); pk.y = pkbf(p2, p3);
                    *(uint2*)&Pw[(size_t)(m * 16 + l15) * LDP + i * 16 + quad * 4] = pk;
                }

            // ---- read P back as A-frags (same-wave LDS RAW)
            bf16x8 pa[2][2];
#pragma unroll
            for (int m = 0; m < 2; ++m) {
                pa[m][0] = *(const bf16x8*)&Pw[(size_t)(m * 16 + l15) * LDP + quad * 8];
                pa[m][1] = *(const bf16x8*)&Pw[(size_t)(m * 16 + l15) * LDP + 32 + quad * 8];
            }

            // ---- l += P @ ones ; O += P V
#pragma unroll
            for (int m = 0; m < 2; ++m) {
                f32x4 z = __builtin_amdgcn_mfma_f32_16x16x32_bf16(pa[m][0], onesf, lac[m], 0, 0, 0);
                lac[m] = __builtin_amdgcn_mfma_f32_16x16x32_bf16(pa[m][1], onesf, z, 0, 0, 0);
            }
#pragma unroll
            for (int dj = 0; dj < 4; ++dj)
#pragma unroll
                for (int m = 0; m < 2; ++m) {
                    f32x4 z = __builtin_amdgcn_mfma_f32_16x16x32_bf16(pa[m][0], vf[dj][0], O[m][dj], 0, 0, 0);
                    O[m][dj] = __builtin_amdgcn_mfma_f32_16x16x32_bf16(pa[m][1], vf[dj][1], z, 0, 0, 0);
                }
        }
    }

    // ---- combine the 4 partial (O,l) via LDS (additive: no max was used)
    __syncthreads();   // all waves done with their P regions
    if (w > 0) {
        float* Ow = Cb + (w - 1) * 2560;
#pragma unroll
        for (int m = 0; m < 2; ++m) {
#pragma unroll
            for (int dj = 0; dj < 4; ++dj)
                *(f32x4*)&Ow[(m * 4 + dj) * 256 + lane * 4] = O[m][dj];
            *(f32x4*)&Ow[2048 + m * 256 + lane * 4] = lac[m];
        }
    }
    __syncthreads();
    if (w == 0) {
#pragma unroll
        for (int c = 0; c < 3; ++c) {
            const float* Ow = Cb + c * 2560;
#pragma unroll
            for (int m = 0; m < 2; ++m) {
#pragma unroll
                for (int dj = 0; dj < 4; ++dj)
                    O[m][dj] += *(const f32x4*)&Ow[(m * 4 + dj) * 256 + lane * 4];
                lac[m] += *(const f32x4*)&Ow[2048 + m * 256 + lane * 4];
            }
        }
        // epilogue: O / l -> Y [b][t][h*64+d] bf16
        const int b = bh / 12, hd = bh % 12;
#pragma unroll
        for (int m = 0; m < 2; ++m)
#pragma unroll
            for (int r = 0; r < 4; ++r) {
                float inv = 1.0f / lac[m][r];
                int t = q0 + 16 * m + quad * 4 + r;
                size_t base = ((size_t)(b * 4096 + t)) * 768 + hd * 64;
#pragma unroll
                for (int dj = 0; dj < 4; ++dj)
                    Y[base + dj * 16 + l15] = f2bf(O[m][dj][r] * inv);
            }
    }
}

// ---------------- launch ----------------
extern "C" void kernel_launch(void* const* d_in, const int* in_sizes, int n_in,
                              void* d_out, int out_size, void* d_ws, size_t ws_size,
                              hipStream_t stream) {
    (void)in_sizes; (void)n_in; (void)out_size; (void)ws_size;
    const float* x     = (const float*)d_in[0];
    const float* Wqkv  = (const float*)d_in[1];
    const float* bqkv  = (const float*)d_in[2];
    const float* Wproj = (const float*)d_in[3];
    const float* bproj = (const float*)d_in[4];
    float* out = (float*)d_out;

    char* ws = (char*)d_ws;
    size_t off = 0;
    auto alloc = [&](size_t bytes) -> void* {
        void* p = ws + off;
        off += (bytes + 255) & ~(size_t)255;
        return p;
    };
    unsigned short* xb     = (unsigned short*)alloc((size_t)8192 * 768 * 2);
    unsigned short* WqkvT  = (unsigned short*)alloc((size_t)2304 * 768 * 2);
    unsigned short* WprojT = (unsigned short*)alloc((size_t)768 * 768 * 2);
    unsigned short* QLb    = (unsigned short*)alloc((size_t)24 * 4096 * 64 * 2);
    unsigned short* KLb    = (unsigned short*)alloc((size_t)24 * 4096 * 64 * 2);
    unsigned short* VLb    = (unsigned short*)alloc((size_t)24 * 4096 * 64 * 2);
    unsigned short* Yb     = (unsigned short*)alloc((size_t)8192 * 768 * 2);

    k_convert<<<6144, 256, 0, stream>>>(x, xb, 8192 * 768 / 4);
    dim3 tb(32, 8);
    k_transpose<<<dim3(72, 24), tb, 0, stream>>>(Wqkv, WqkvT, 768, 2304);
    k_transpose<<<dim3(24, 24), tb, 0, stream>>>(Wproj, WprojT, 768, 768);
    k_gemm_qkv<<<dim3(64, 18), 256, 0, stream>>>(xb, WqkvT, bqkv, QLb, KLb, VLb);
    k_attn<<<dim3(3072), 256, 0, stream>>>(QLb, KLb, VLb, Yb);
    k_gemm_proj<<<dim3(64, 6), 256, 0, stream>>>(Yb, WprojT, bproj, out);
}

// Round 7
// 262.204 us; speedup vs baseline: 2.2222x; 1.0365x over previous
//
#include <hip/hip_runtime.h>
#include <math.h>
#include <stdint.h>

// MFMA fragment types (guide §3, compile-verified on gfx950)
typedef __attribute__((ext_vector_type(8))) short bf16x8;   // 8 bf16 in 4 VGPRs
typedef __attribute__((ext_vector_type(4))) float f32x4;    // 4 fp32 acc

__device__ __forceinline__ unsigned short f2bf(float f) {
    union { float f; unsigned u; } v; v.f = f;
    return (unsigned short)((v.u + 0x7fffu + ((v.u >> 16) & 1u)) >> 16); // RNE
}

// async global->LDS, 16B per lane; LDS dest = firstlane base + lane*16 (m97)
__device__ __forceinline__ void gld_lds16(const void* g, void* l) {
    __builtin_amdgcn_global_load_lds(
        (const __attribute__((address_space(1))) unsigned*)(uintptr_t)g,
        (__attribute__((address_space(3))) unsigned*)(uintptr_t)l, 16, 0, 0);
}

// ---------------- fp32 -> bf16 elementwise (x4 vectorized) ----------------
__global__ void k_convert(const float* __restrict__ in, unsigned short* __restrict__ out, int n4) {
    int i = blockIdx.x * blockDim.x + threadIdx.x;
    if (i >= n4) return;
    float4 f = ((const float4*)in)[i];
    ushort4 o;
    o.x = f2bf(f.x); o.y = f2bf(f.y); o.z = f2bf(f.z); o.w = f2bf(f.w);
    ((ushort4*)out)[i] = o;
}

// ---------------- fp32 [R][C] -> bf16 [C][R] (tiled transpose) ----------------
__global__ void k_transpose(const float* __restrict__ in, unsigned short* __restrict__ out, int R, int C) {
    __shared__ float tile[32][33];
    int c0 = blockIdx.x * 32, r0 = blockIdx.y * 32;
    int tx = threadIdx.x, ty = threadIdx.y; // block (32,8)
#pragma unroll
    for (int i = 0; i < 4; ++i)
        tile[ty + i * 8][tx] = in[(size_t)(r0 + ty + i * 8) * C + c0 + tx];
    __syncthreads();
#pragma unroll
    for (int i = 0; i < 4; ++i)
        out[(size_t)(c0 + ty + i * 8) * R + r0 + tx] = f2bf(tile[tx][ty + i * 8]);
}

// ---------------- 128x128 bf16 MFMA GEMM core (m97-style staging) ----------
// LDS tiles are unpadded 128x32 (global_load_lds needs lane-contiguous dest:
// thread tid's chunk lands at byte tid*16). 2-barrier K-loop, 16B async loads.
#define LDT 32

__device__ __forceinline__ void gemm_core(
    const unsigned short* __restrict__ A, const unsigned short* __restrict__ Bt,
    int K, unsigned short* As, unsigned short* Bs, f32x4 (&acc)[4][4])
{
    const int tid  = threadIdx.x;
    const int lane = tid & 63;
    const int w    = tid >> 6;
    const int wm   = (w >> 1) * 64, wn = (w & 1) * 64;
    const int l15  = lane & 15, quad = lane >> 4;
    const int m0 = blockIdx.x * 128, n0 = blockIdx.y * 128;

    const f32x4 zero = {0.f, 0.f, 0.f, 0.f};
#pragma unroll
    for (int i = 0; i < 4; ++i)
#pragma unroll
        for (int j = 0; j < 4; ++j) acc[i][j] = zero;

    const int r0 = tid >> 2, p8 = (tid & 3) * 8;
    const unsigned short* Ag0 = A  + (size_t)(m0 + r0) * K + p8;
    const unsigned short* Ag1 = A  + (size_t)(m0 + r0 + 64) * K + p8;
    const unsigned short* Bg0 = Bt + (size_t)(n0 + r0) * K + p8;
    const unsigned short* Bg1 = Bt + (size_t)(n0 + r0 + 64) * K + p8;
    unsigned short* lA0 = As + r0 * LDT + p8;          // byte offset tid*16
    unsigned short* lA1 = lA0 + 64 * LDT;
    unsigned short* lB0 = Bs + r0 * LDT + p8;
    unsigned short* lB1 = lB0 + 64 * LDT;

    const int nk = K >> 5;
    for (int kt = 0; kt < nk; ++kt) {
        __syncthreads();                    // LDS free (prev compute done)
        gld_lds16(Ag0, lA0);
        gld_lds16(Ag1, lA1);
        gld_lds16(Bg0, lB0);
        gld_lds16(Bg1, lB1);
        Ag0 += 32; Ag1 += 32; Bg0 += 32; Bg1 += 32;
        __syncthreads();                    // drains vmcnt -> data landed
        bf16x8 af[4], bfr[4];
#pragma unroll
        for (int mi = 0; mi < 4; ++mi)
            af[mi] = *(const bf16x8*)&As[(wm + mi * 16 + l15) * LDT + quad * 8];
#pragma unroll
        for (int nj = 0; nj < 4; ++nj)
            bfr[nj] = *(const bf16x8*)&Bs[(wn + nj * 16 + l15) * LDT + quad * 8];
#pragma unroll
        for (int mi = 0; mi < 4; ++mi)
#pragma unroll
            for (int nj = 0; nj < 4; ++nj)
                acc[mi][nj] = __builtin_amdgcn_mfma_f32_16x16x32_bf16(af[mi], bfr[nj], acc[mi][nj], 0, 0, 0);
    }
}

// QKV GEMM epilogue scatters into FRAGMENT-ORDER buffers so every attention
// global load is one coalesced 1024B block (base + lane*16B):
//  QL[bh][qi][m][h][lane][8]  : lane(l15,quad) holds Q[qi*32+16m+l15][32h+8quad+j]
//  KL[bh][t ][i][h][lane][8]  : lane holds K[64t+16i+l15][32h+8quad+j]
//  VL[bh][t ][dj][h][lane][8] : lane holds V[64t+32h+8quad+j][16dj+l15]
// Q pre-scaled by (1/8)*log2(e): softmax runs in exp2 domain.
__global__ __launch_bounds__(256) void k_gemm_qkv(
    const unsigned short* __restrict__ A, const unsigned short* __restrict__ Bt,
    const float* __restrict__ bias,
    unsigned short* __restrict__ QL, unsigned short* __restrict__ KL,
    unsigned short* __restrict__ VL)
{
    __shared__ __align__(16) unsigned short As[128 * LDT];
    __shared__ __align__(16) unsigned short Bs[128 * LDT];
    f32x4 acc[4][4];
    gemm_core(A, Bt, 768, As, Bs, acc);

    const int tid = threadIdx.x, lane = tid & 63, w = tid >> 6;
    const int wm = (w >> 1) * 64, wn = (w & 1) * 64;
    const int l15 = lane & 15, quad = lane >> 4;
    const int m0 = blockIdx.x * 128, n0 = blockIdx.y * 128;
    const float cscale = 0.18033688011f;  // (1/8) * log2(e)
#pragma unroll
    for (int nj = 0; nj < 4; ++nj) {
        int cg = n0 + wn + nj * 16 + l15;        // column in [0,2304)
        float bv = bias[cg];
        int which = cg / 768;                    // 0=q 1=k 2=v
        int rem = cg - which * 768;
        int hd = rem >> 6, d = rem & 63;
        float sc = (which == 0) ? cscale : 1.0f;
#pragma unroll
        for (int mi = 0; mi < 4; ++mi) {
#pragma unroll
            for (int r = 0; r < 4; ++r) {
                int rg = m0 + wm + mi * 16 + quad * 4 + r;   // row in [0,8192)
                int b = rg >> 12, tk = rg & 4095;
                int bh = b * 12 + hd;
                unsigned short ob = f2bf((acc[mi][nj][r] + bv) * sc);
                if (which == 0) {
                    size_t idx = ((((size_t)bh * 128 + (tk >> 5)) * 2 + ((tk >> 4) & 1)) * 2 + (d >> 5)) * 512
                               + ((d >> 3) & 3) * 128 + (tk & 15) * 8 + (d & 7);
                    QL[idx] = ob;
                } else if (which == 1) {
                    size_t idx = ((((size_t)bh * 64 + (tk >> 6)) * 4 + ((tk >> 4) & 3)) * 2 + (d >> 5)) * 512
                               + ((d >> 3) & 3) * 128 + (tk & 15) * 8 + (d & 7);
                    KL[idx] = ob;
                } else {
                    int wi = tk & 63;
                    size_t idx = ((((size_t)bh * 64 + (tk >> 6)) * 4 + (d >> 4)) * 2 + (wi >> 5)) * 512
                               + ((wi >> 3) & 3) * 128 + (d & 15) * 8 + (wi & 7);
                    VL[idx] = ob;
                }
            }
        }
    }
}

// Proj GEMM: A = y bf16 [8192][768], Bt = WprojT [768][768], out fp32 + bias
__global__ __launch_bounds__(256) void k_gemm_proj(
    const unsigned short* __restrict__ A, const unsigned short* __restrict__ Bt,
    const float* __restrict__ bias, float* __restrict__ out)
{
    __shared__ __align__(16) unsigned short As[128 * LDT];
    __shared__ __align__(16) unsigned short Bs[128 * LDT];
    f32x4 acc[4][4];
    gemm_core(A, Bt, 768, As, Bs, acc);

    const int tid = threadIdx.x, lane = tid & 63, w = tid >> 6;
    const int wm = (w >> 1) * 64, wn = (w & 1) * 64;
    const int l15 = lane & 15, quad = lane >> 4;
    const int m0 = blockIdx.x * 128, n0 = blockIdx.y * 128;
#pragma unroll
    for (int nj = 0; nj < 4; ++nj) {
        int cg = n0 + wn + nj * 16 + l15;
        float bv = bias[cg];
#pragma unroll
        for (int mi = 0; mi < 4; ++mi)
#pragma unroll
            for (int r = 0; r < 4; ++r) {
                int rg = m0 + wm + mi * 16 + quad * 4 + r;
                out[(size_t)rg * 768 + cg] = acc[mi][nj][r] + bv;
            }
    }
}

// ---------------- Flash attention, causal, split-K, XCD-local ----------------
// grid id = qidx*24 + bh => XCD = id%8 = bh%8: 3 heads/XCD, K+V set 3MB < L2.
// Block = 4 waves over the SAME 32 q-rows; wave c handles key tiles
// [c*nkt/4,(c+1)*nkt/4). No-max exp2 softmax => partials additive; combined
// via LDS at block end. All Q/K/V loads are coalesced 1024B fragment blocks.
// R7 VALU diet: readfirstlane(w) -> scalar loop bounds/LDS bases; K/V pointer
// induction (no per-load 64b muls); hoisted int LDS offsets (imm-offset DS);
// v_perm bf16 pack; raw v_exp_f32. No min-waves bound (R5: (256,4) => spills).
#define LDP 72   // P row stride in shorts; 144B rows keep ds_read_b128 16B-aligned

__global__ __launch_bounds__(256) void k_attn(
    const unsigned short* __restrict__ QL, const unsigned short* __restrict__ KL,
    const unsigned short* __restrict__ VL, unsigned short* __restrict__ Y)
{
    // P regions (4 x 32 x LDP shorts = 18432B) and combine buffer (30720B):
    // disjoint lifetimes -> union.
    __shared__ __align__(16) char smem[30720];
    unsigned short* Ps = (unsigned short*)smem;
    float* Cb = (float*)smem;

    const int tid = threadIdx.x, lane = tid & 63;
    const int w = __builtin_amdgcn_readfirstlane(tid >> 6);   // wave-uniform
    const int l15 = lane & 15, quad = lane >> 4;
    const int id = blockIdx.x;
    const int bh = id % 24;
    const int qi = 127 - id / 24;                     // longest first
    const int q0 = qi * 32;
    const int nkt = qi / 2 + 1;                       // 64-key tiles (causal)
    const int lo = (nkt * w) >> 2, hi = (nkt * (w + 1)) >> 2;
    unsigned short* Pw = Ps + w * 32 * LDP;

    // hoisted LDS addresses (loop-invariant; DS imm offsets cover (m,i,h))
    unsigned short* pwb = Pw + l15 * LDP + quad * 4;          // writes
    const unsigned short* prb = Pw + l15 * LDP + quad * 8;    // reads

    // fragment-chunk bases (each chunk = 512 shorts = 1024B, lane offset *8)
    const unsigned short* Qb = QL + (((size_t)bh * 128 + qi) * 4) * 512 + lane * 8;
    const unsigned short* kp = KL + ((size_t)bh * 64 + lo) * 8 * 512 + lane * 8;
    const unsigned short* vp = VL + ((size_t)bh * 64 + lo) * 8 * 512 + lane * 8;

    // Q^T B-fragments (chunk layout matches B-frag exactly)
    bf16x8 qt[2][2];
#pragma unroll
    for (int m = 0; m < 2; ++m)
#pragma unroll
        for (int h = 0; h < 2; ++h)
            qt[m][h] = *(const bf16x8*)(Qb + (m * 2 + h) * 512);

    const f32x4 zero = {0.f, 0.f, 0.f, 0.f};
    f32x4 O[2][4], lac[2];
#pragma unroll
    for (int m = 0; m < 2; ++m) {
        lac[m] = zero;
#pragma unroll
        for (int dj = 0; dj < 4; ++dj) O[m][dj] = zero;
    }

    const short ONE = (short)0x3F80;  // bf16 1.0
    const bf16x8 onesf = {ONE, ONE, ONE, ONE, ONE, ONE, ONE, ONE};

    if (lo < hi) {
        // K A-fragments for first tile
        bf16x8 ka[4][2];
#pragma unroll
        for (int i = 0; i < 4; ++i)
#pragma unroll
            for (int h = 0; h < 2; ++h)
                ka[i][h] = *(const bf16x8*)(kp + (i * 2 + h) * 512);

        for (int kt = lo; kt < hi; ++kt) {
            // ---- S^T = K Q^T : lane holds (key = i*16+quad*4+r, qrow = m*16+l15)
            f32x4 st[2][4];
#pragma unroll
            for (int i = 0; i < 4; ++i)
#pragma unroll
                for (int m = 0; m < 2; ++m) {
                    f32x4 z = __builtin_amdgcn_mfma_f32_16x16x32_bf16(ka[i][0], qt[m][0], zero, 0, 0, 0);
                    st[m][i] = __builtin_amdgcn_mfma_f32_16x16x32_bf16(ka[i][1], qt[m][1], z, 0, 0, 0);
                }

            // ---- V B-fragments for this tile (pointer induction, imm offsets)
            bf16x8 vf[4][2];
#pragma unroll
            for (int dj = 0; dj < 4; ++dj)
#pragma unroll
                for (int h = 0; h < 2; ++h)
                    vf[dj][h] = *(const bf16x8*)(vp + (dj * 2 + h) * 512);
            vp += 8 * 512;

            // ---- K prefetch for next tile
            if (kt + 1 < hi) {
                kp += 8 * 512;
#pragma unroll
                for (int i = 0; i < 4; ++i)
#pragma unroll
                    for (int h = 0; h < 2; ++h)
                        ka[i][h] = *(const bf16x8*)(kp + (i * 2 + h) * 512);
            }

            // ---- causal mask on diagonal tile (always owned by wave 3)
            if (kt == nkt - 1) {
                const int kb = kt * 64;
#pragma unroll
                for (int m = 0; m < 2; ++m)
#pragma unroll
                    for (int i = 0; i < 4; ++i)
#pragma unroll
                        for (int r = 0; r < 4; ++r)
                            if (kb + i * 16 + quad * 4 + r > q0 + m * 16 + l15)
                                st[m][i][r] = -INFINITY;
            }

            // ---- p = exp2(s) (no max; logits sigma~1.4, fp32-safe);
            //      bf16 pack: +0x8000 round + one v_perm per pair
#pragma unroll
            for (int m = 0; m < 2; ++m)
#pragma unroll
                for (int i = 0; i < 4; ++i) {
                    unsigned e0 = __float_as_uint(__builtin_amdgcn_exp2f(fminf(st[m][i][0], 80.f))) + 0x8000u;
                    unsigned e1 = __float_as_uint(__builtin_amdgcn_exp2f(fminf(st[m][i][1], 80.f))) + 0x8000u;
                    unsigned e2 = __float_as_uint(__builtin_amdgcn_exp2f(fminf(st[m][i][2], 80.f))) + 0x8000u;
                    unsigned e3 = __float_as_uint(__builtin_amdgcn_exp2f(fminf(st[m][i][3], 80.f))) + 0x8000u;
                    uint2 pk;
                    pk.x = __builtin_amdgcn_perm(e1, e0, 0x07060302);
                    pk.y = __builtin_amdgcn_perm(e3, e2, 0x07060302);
                    *(uint2*)(pwb + m * 16 * LDP + i * 16) = pk;
                }

            // ---- read P back as A-frags (same-wave LDS RAW)
            bf16x8 pa[2][2];
#pragma unroll
            for (int m = 0; m < 2; ++m) {
                pa[m][0] = *(const bf16x8*)(prb + m * 16 * LDP);
                pa[m][1] = *(const bf16x8*)(prb + m * 16 * LDP + 32);
            }

            // ---- l += P @ ones ; O += P V
#pragma unroll
            for (int m = 0; m < 2; ++m) {
                f32x4 z = __builtin_amdgcn_mfma_f32_16x16x32_bf16(pa[m][0], onesf, lac[m], 0, 0, 0);
                lac[m] = __builtin_amdgcn_mfma_f32_16x16x32_bf16(pa[m][1], onesf, z, 0, 0, 0);
            }
#pragma unroll
            for (int dj = 0; dj < 4; ++dj)
#pragma unroll
                for (int m = 0; m < 2; ++m) {
                    f32x4 z = __builtin_amdgcn_mfma_f32_16x16x32_bf16(pa[m][0], vf[dj][0], O[m][dj], 0, 0, 0);
                    O[m][dj] = __builtin_amdgcn_mfma_f32_16x16x32_bf16(pa[m][1], vf[dj][1], z, 0, 0, 0);
                }
        }
    }

    // ---- combine the 4 partial (O,l) via LDS (additive: no max was used)
    __syncthreads();   // all waves done with their P regions
    if (w > 0) {
        float* Ow = Cb + (w - 1) * 2560;
#pragma unroll
        for (int m = 0; m < 2; ++m) {
#pragma unroll
            for (int dj = 0; dj < 4; ++dj)
                *(f32x4*)&Ow[(m * 4 + dj) * 256 + lane * 4] = O[m][dj];
            *(f32x4*)&Ow[2048 + m * 256 + lane * 4] = lac[m];
        }
    }
    __syncthreads();
    if (w == 0) {
#pragma unroll
        for (int c = 0; c < 3; ++c) {
            const float* Ow = Cb + c * 2560;
#pragma unroll
            for (int m = 0; m < 2; ++m) {
#pragma unroll
                for (int dj = 0; dj < 4; ++dj)
                    O[m][dj] += *(const f32x4*)&Ow[(m * 4 + dj) * 256 + lane * 4];
                lac[m] += *(const f32x4*)&Ow[2048 + m * 256 + lane * 4];
            }
        }
        // epilogue: O / l -> Y [b][t][h*64+d] bf16
        const int b = bh / 12, hd = bh % 12;
#pragma unroll
        for (int m = 0; m < 2; ++m)
#pragma unroll
            for (int r = 0; r < 4; ++r) {
                float inv = 1.0f / lac[m][r];
                int t = q0 + 16 * m + quad * 4 + r;
                size_t base = ((size_t)(b * 4096 + t)) * 768 + hd * 64;
#pragma unroll
                for (int dj = 0; dj < 4; ++dj)
                    Y[base + dj * 16 + l15] = f2bf(O[m][dj][r] * inv);
            }
    }
}

// ---------------- launch ----------------
extern "C" void kernel_launch(void* const* d_in, const int* in_sizes, int n_in,
                              void* d_out, int out_size, void* d_ws, size_t ws_size,
                              hipStream_t stream) {
    (void)in_sizes; (void)n_in; (void)out_size; (void)ws_size;
    const float* x     = (const float*)d_in[0];
    const float* Wqkv  = (const float*)d_in[1];
    const float* bqkv  = (const float*)d_in[2];
    const float* Wproj = (const float*)d_in[3];
    const float* bproj = (const float*)d_in[4];
    float* out = (float*)d_out;

    char* ws = (char*)d_ws;
    size_t off = 0;
    auto alloc = [&](size_t bytes) -> void* {
        void* p = ws + off;
        off += (bytes + 255) & ~(size_t)255;
        return p;
    };
    unsigned short* xb     = (unsigned short*)alloc((size_t)8192 * 768 * 2);
    unsigned short* WqkvT  = (unsigned short*)alloc((size_t)2304 * 768 * 2);
    unsigned short* WprojT = (unsigned short*)alloc((size_t)768 * 768 * 2);
    unsigned short* QLb    = (unsigned short*)alloc((size_t)24 * 4096 * 64 * 2);
    unsigned short* KLb    = (unsigned short*)alloc((size_t)24 * 4096 * 64 * 2);
    unsigned short* VLb    = (unsigned short*)alloc((size_t)24 * 4096 * 64 * 2);
    unsigned short* Yb     = (unsigned short*)alloc((size_t)8192 * 768 * 2);

    k_convert<<<6144, 256, 0, stream>>>(x, xb, 8192 * 768 / 4);
    dim3 tb(32, 8);
    k_transpose<<<dim3(72, 24), tb, 0, stream>>>(Wqkv, WqkvT, 768, 2304);
    k_transpose<<<dim3(24, 24), tb, 0, stream>>>(Wproj, WprojT, 768, 768);
    k_gemm_qkv<<<dim3(64, 18), 256, 0, stream>>>(xb, WqkvT, bqkv, QLb, KLb, VLb);
    k_attn<<<dim3(3072), 256, 0, stream>>>(QLb, KLb, VLb, Yb);
    k_gemm_proj<<<dim3(64, 6), 256, 0, stream>>>(Yb, WprojT, bproj, out);
}

// Round 8
// 255.294 us; speedup vs baseline: 2.2823x; 1.0271x over previous
//
#include <hip/hip_runtime.h>
#include <math.h>
#include <stdint.h>

// MFMA fragment types (guide §3, compile-verified on gfx950)
typedef __attribute__((ext_vector_type(8))) short bf16x8;   // 8 bf16 in 4 VGPRs
typedef __attribute__((ext_vector_type(4))) float f32x4;    // 4 fp32 acc

__device__ __forceinline__ unsigned short f2bf(float f) {
    union { float f; unsigned u; } v; v.f = f;
    return (unsigned short)((v.u + 0x7fffu + ((v.u >> 16) & 1u)) >> 16); // RNE
}

// async global->LDS, 16B per lane; LDS dest = firstlane base + lane*16 (m97)
__device__ __forceinline__ void gld_lds16(const void* g, void* l) {
    __builtin_amdgcn_global_load_lds(
        (const __attribute__((address_space(1))) unsigned*)(uintptr_t)g,
        (__attribute__((address_space(3))) unsigned*)(uintptr_t)l, 16, 0, 0);
}

// ---------------- fp32 -> bf16 elementwise (x4 vectorized) ----------------
__global__ void k_convert(const float* __restrict__ in, unsigned short* __restrict__ out, int n4) {
    int i = blockIdx.x * blockDim.x + threadIdx.x;
    if (i >= n4) return;
    float4 f = ((const float4*)in)[i];
    ushort4 o;
    o.x = f2bf(f.x); o.y = f2bf(f.y); o.z = f2bf(f.z); o.w = f2bf(f.w);
    ((ushort4*)out)[i] = o;
}

// ---------------- fp32 [R][C] -> bf16 [C][R] (tiled transpose) ----------------
__global__ void k_transpose(const float* __restrict__ in, unsigned short* __restrict__ out, int R, int C) {
    __shared__ float tile[32][33];
    int c0 = blockIdx.x * 32, r0 = blockIdx.y * 32;
    int tx = threadIdx.x, ty = threadIdx.y; // block (32,8)
#pragma unroll
    for (int i = 0; i < 4; ++i)
        tile[ty + i * 8][tx] = in[(size_t)(r0 + ty + i * 8) * C + c0 + tx];
    __syncthreads();
#pragma unroll
    for (int i = 0; i < 4; ++i)
        out[(size_t)(c0 + ty + i * 8) * R + r0 + tx] = f2bf(tile[tx][ty + i * 8]);
}

// ---------------- 128x128 bf16 MFMA GEMM core (m97-style staging) ----------
#define LDT 32

__device__ __forceinline__ void gemm_core(
    const unsigned short* __restrict__ A, const unsigned short* __restrict__ Bt,
    int K, unsigned short* As, unsigned short* Bs, f32x4 (&acc)[4][4])
{
    const int tid  = threadIdx.x;
    const int lane = tid & 63;
    const int w    = tid >> 6;
    const int wm   = (w >> 1) * 64, wn = (w & 1) * 64;
    const int l15  = lane & 15, quad = lane >> 4;
    const int m0 = blockIdx.x * 128, n0 = blockIdx.y * 128;

    const f32x4 zero = {0.f, 0.f, 0.f, 0.f};
#pragma unroll
    for (int i = 0; i < 4; ++i)
#pragma unroll
        for (int j = 0; j < 4; ++j) acc[i][j] = zero;

    const int r0 = tid >> 2, p8 = (tid & 3) * 8;
    const unsigned short* Ag0 = A  + (size_t)(m0 + r0) * K + p8;
    const unsigned short* Ag1 = A  + (size_t)(m0 + r0 + 64) * K + p8;
    const unsigned short* Bg0 = Bt + (size_t)(n0 + r0) * K + p8;
    const unsigned short* Bg1 = Bt + (size_t)(n0 + r0 + 64) * K + p8;
    unsigned short* lA0 = As + r0 * LDT + p8;          // byte offset tid*16
    unsigned short* lA1 = lA0 + 64 * LDT;
    unsigned short* lB0 = Bs + r0 * LDT + p8;
    unsigned short* lB1 = lB0 + 64 * LDT;

    const int nk = K >> 5;
    for (int kt = 0; kt < nk; ++kt) {
        __syncthreads();                    // LDS free (prev compute done)
        gld_lds16(Ag0, lA0);
        gld_lds16(Ag1, lA1);
        gld_lds16(Bg0, lB0);
        gld_lds16(Bg1, lB1);
        Ag0 += 32; Ag1 += 32; Bg0 += 32; Bg1 += 32;
        __syncthreads();                    // drains vmcnt -> data landed
        bf16x8 af[4], bfr[4];
#pragma unroll
        for (int mi = 0; mi < 4; ++mi)
            af[mi] = *(const bf16x8*)&As[(wm + mi * 16 + l15) * LDT + quad * 8];
#pragma unroll
        for (int nj = 0; nj < 4; ++nj)
            bfr[nj] = *(const bf16x8*)&Bs[(wn + nj * 16 + l15) * LDT + quad * 8];
#pragma unroll
        for (int mi = 0; mi < 4; ++mi)
#pragma unroll
            for (int nj = 0; nj < 4; ++nj)
                acc[mi][nj] = __builtin_amdgcn_mfma_f32_16x16x32_bf16(af[mi], bfr[nj], acc[mi][nj], 0, 0, 0);
    }
}

// QKV GEMM epilogue scatters into FRAGMENT-ORDER buffers so every attention
// global load is one coalesced 1024B block (base + lane*16B):
//  QL[bh][qi][m][h][lane][8]  : lane(l15,quad) holds Q[qi*32+16m+l15][32h+8quad+j]
//  KL[bh][t ][i][h][lane][8]  : lane holds K[64t+16i+l15][32h+8quad+j]
//  VL[bh][t ][dj][h][lane][8] : lane holds V[64t+32h+8quad+j][16dj+l15]
// Q pre-scaled by (1/8)*log2(e): softmax runs in exp2 domain.
__global__ __launch_bounds__(256) void k_gemm_qkv(
    const unsigned short* __restrict__ A, const unsigned short* __restrict__ Bt,
    const float* __restrict__ bias,
    unsigned short* __restrict__ QL, unsigned short* __restrict__ KL,
    unsigned short* __restrict__ VL)
{
    __shared__ __align__(16) unsigned short As[128 * LDT];
    __shared__ __align__(16) unsigned short Bs[128 * LDT];
    f32x4 acc[4][4];
    gemm_core(A, Bt, 768, As, Bs, acc);

    const int tid = threadIdx.x, lane = tid & 63, w = tid >> 6;
    const int wm = (w >> 1) * 64, wn = (w & 1) * 64;
    const int l15 = lane & 15, quad = lane >> 4;
    const int m0 = blockIdx.x * 128, n0 = blockIdx.y * 128;
    const float cscale = 0.18033688011f;  // (1/8) * log2(e)
#pragma unroll
    for (int nj = 0; nj < 4; ++nj) {
        int cg = n0 + wn + nj * 16 + l15;        // column in [0,2304)
        float bv = bias[cg];
        int which = cg / 768;                    // 0=q 1=k 2=v
        int rem = cg - which * 768;
        int hd = rem >> 6, d = rem & 63;
        float sc = (which == 0) ? cscale : 1.0f;
#pragma unroll
        for (int mi = 0; mi < 4; ++mi) {
#pragma unroll
            for (int r = 0; r < 4; ++r) {
                int rg = m0 + wm + mi * 16 + quad * 4 + r;   // row in [0,8192)
                int b = rg >> 12, tk = rg & 4095;
                int bh = b * 12 + hd;
                unsigned short ob = f2bf((acc[mi][nj][r] + bv) * sc);
                if (which == 0) {
                    size_t idx = ((((size_t)bh * 128 + (tk >> 5)) * 2 + ((tk >> 4) & 1)) * 2 + (d >> 5)) * 512
                               + ((d >> 3) & 3) * 128 + (tk & 15) * 8 + (d & 7);
                    QL[idx] = ob;
                } else if (which == 1) {
                    size_t idx = ((((size_t)bh * 64 + (tk >> 6)) * 4 + ((tk >> 4) & 3)) * 2 + (d >> 5)) * 512
                               + ((d >> 3) & 3) * 128 + (tk & 15) * 8 + (d & 7);
                    KL[idx] = ob;
                } else {
                    int wi = tk & 63;
                    size_t idx = ((((size_t)bh * 64 + (tk >> 6)) * 4 + (d >> 4)) * 2 + (wi >> 5)) * 512
                               + ((wi >> 3) & 3) * 128 + (d & 15) * 8 + (wi & 7);
                    VL[idx] = ob;
                }
            }
        }
    }
}

// Proj GEMM: A = y bf16 [8192][768], Bt = WprojT [768][768], out fp32 + bias
__global__ __launch_bounds__(256) void k_gemm_proj(
    const unsigned short* __restrict__ A, const unsigned short* __restrict__ Bt,
    const float* __restrict__ bias, float* __restrict__ out)
{
    __shared__ __align__(16) unsigned short As[128 * LDT];
    __shared__ __align__(16) unsigned short Bs[128 * LDT];
    f32x4 acc[4][4];
    gemm_core(A, Bt, 768, As, Bs, acc);

    const int tid = threadIdx.x, lane = tid & 63, w = tid >> 6;
    const int wm = (w >> 1) * 64, wn = (w & 1) * 64;
    const int l15 = lane & 15, quad = lane >> 4;
    const int m0 = blockIdx.x * 128, n0 = blockIdx.y * 128;
#pragma unroll
    for (int nj = 0; nj < 4; ++nj) {
        int cg = n0 + wn + nj * 16 + l15;
        float bv = bias[cg];
#pragma unroll
        for (int mi = 0; mi < 4; ++mi)
#pragma unroll
            for (int r = 0; r < 4; ++r) {
                int rg = m0 + wm + mi * 16 + quad * 4 + r;
                out[(size_t)rg * 768 + cg] = acc[mi][nj][r] + bv;
            }
    }
}

// ---------------- Flash attention, causal, split-K, XCD-local, PIPELINED ----
// grid id = qidx*24 + bh => XCD = id%8 = bh%8: 3 heads/XCD, K+V set 3MB < L2.
// Block = 4 waves over the SAME 32 q-rows; wave c handles key tiles
// [c*nkt/4,(c+1)*nkt/4); additive no-max exp2 partials combined via LDS.
// Software pipeline (one-iteration skew, P double-buffered in LDS):
//   iter kt: read P(kt) [written last iter -> no RAW stall] ; issue ka(kt+1) ;
//   l/O MFMAs (cover ka latency) ; issue vf(kt+1) ; QK(kt+1) ; exp2 (covers
//   vf latency) ; write P(kt+1) to other buffer.
// LDP=68 (136B rows): l15*34%32 = l15*2 -> conflict-free (R6: 0 conflicts;
// R7's LDP=72 cost 4.8M conflict cycles).
#define LDP 68

__global__ __launch_bounds__(256) void k_attn(
    const unsigned short* __restrict__ QL, const unsigned short* __restrict__ KL,
    const unsigned short* __restrict__ VL, unsigned short* __restrict__ Y)
{
    // P dbuf: 4 waves x 2 bufs x 32*LDP shorts = 34816B; combine buffer
    // (3 x 2560 floats = 30720B) has disjoint lifetime -> union.
    __shared__ __align__(16) char smem[34816];
    unsigned short* Ps = (unsigned short*)smem;
    float* Cb = (float*)smem;

    const int tid = threadIdx.x, lane = tid & 63;
    const int w = __builtin_amdgcn_readfirstlane(tid >> 6);   // wave-uniform
    const int l15 = lane & 15, quad = lane >> 4;
    const int id = blockIdx.x;
    const int bh = id % 24;
    const int qi = 127 - id / 24;                     // longest first
    const int q0 = qi * 32;
    const int nkt = qi / 2 + 1;                       // 64-key tiles (causal)
    const int lo = (nkt * w) >> 2, hi = (nkt * (w + 1)) >> 2;
    unsigned short* Pw = Ps + w * 2 * 32 * LDP;       // this wave's two buffers

    const int pw_off = l15 * LDP + quad * 4;          // P write base (shorts)
    const int pr_off = l15 * LDP + quad * 8;          // P read base

    // fragment-chunk bases (each chunk = 512 shorts = 1024B, lane offset *8)
    const unsigned short* Qb = QL + (((size_t)bh * 128 + qi) * 4) * 512 + lane * 8;
    const unsigned short* kp = KL + ((size_t)bh * 64 + lo) * 4096 + lane * 8;
    const unsigned short* vp = VL + ((size_t)bh * 64 + lo) * 4096 + lane * 8;

    // Q^T B-fragments (chunk layout matches B-frag exactly)
    bf16x8 qt[2][2];
#pragma unroll
    for (int m = 0; m < 2; ++m)
#pragma unroll
        for (int h = 0; h < 2; ++h)
            qt[m][h] = *(const bf16x8*)(Qb + (m * 2 + h) * 512);

    const f32x4 zero = {0.f, 0.f, 0.f, 0.f};
    f32x4 O[2][4], lac[2];
#pragma unroll
    for (int m = 0; m < 2; ++m) {
        lac[m] = zero;
#pragma unroll
        for (int dj = 0; dj < 4; ++dj) O[m][dj] = zero;
    }

    const short ONE = (short)0x3F80;  // bf16 1.0
    const bf16x8 onesf = {ONE, ONE, ONE, ONE, ONE, ONE, ONE, ONE};

    if (lo < hi) {
        bf16x8 ka[4][2], vf[4][2];
#pragma unroll
        for (int i = 0; i < 4; ++i)
#pragma unroll
            for (int h = 0; h < 2; ++h)
                ka[i][h] = *(const bf16x8*)(kp + (i * 2 + h) * 512);
#pragma unroll
        for (int dj = 0; dj < 4; ++dj)
#pragma unroll
            for (int h = 0; h < 2; ++h)
                vf[dj][h] = *(const bf16x8*)(vp + (dj * 2 + h) * 512);

        // ---- prologue: st(lo) -> exp2 -> P buf0
        {
            f32x4 st[2][4];
#pragma unroll
            for (int i = 0; i < 4; ++i)
#pragma unroll
                for (int m = 0; m < 2; ++m) {
                    f32x4 z = __builtin_amdgcn_mfma_f32_16x16x32_bf16(ka[i][0], qt[m][0], zero, 0, 0, 0);
                    st[m][i] = __builtin_amdgcn_mfma_f32_16x16x32_bf16(ka[i][1], qt[m][1], z, 0, 0, 0);
                }
            if (lo == nkt - 1) {
                const int kb = lo * 64;
#pragma unroll
                for (int m = 0; m < 2; ++m)
#pragma unroll
                    for (int i = 0; i < 4; ++i)
#pragma unroll
                        for (int r = 0; r < 4; ++r)
                            if (kb + i * 16 + quad * 4 + r > q0 + m * 16 + l15)
                                st[m][i][r] = -INFINITY;
            }
#pragma unroll
            for (int m = 0; m < 2; ++m)
#pragma unroll
                for (int i = 0; i < 4; ++i) {
                    unsigned e0 = __float_as_uint(__builtin_amdgcn_exp2f(st[m][i][0])) + 0x8000u;
                    unsigned e1 = __float_as_uint(__builtin_amdgcn_exp2f(st[m][i][1])) + 0x8000u;
                    unsigned e2 = __float_as_uint(__builtin_amdgcn_exp2f(st[m][i][2])) + 0x8000u;
                    unsigned e3 = __float_as_uint(__builtin_amdgcn_exp2f(st[m][i][3])) + 0x8000u;
                    uint2 pk;
                    pk.x = __builtin_amdgcn_perm(e1, e0, 0x07060302);
                    pk.y = __builtin_amdgcn_perm(e3, e2, 0x07060302);
                    *(uint2*)(Pw + pw_off + m * 16 * LDP + i * 16) = pk;
                }
        }

        for (int kt = lo; kt < hi; ++kt) {
            unsigned short* bc = Pw + ((kt - lo) & 1) * 32 * LDP;
            unsigned short* bn = Pw + (((kt - lo) & 1) ^ 1) * 32 * LDP;
            const bool more = (kt + 1 < hi);

            // ---- read P(kt) as A-frags (written last iter; no RAW stall)
            bf16x8 pa[2][2];
#pragma unroll
            for (int m = 0; m < 2; ++m) {
                pa[m][0] = *(const bf16x8*)(bc + pr_off + m * 16 * LDP);
                pa[m][1] = *(const bf16x8*)(bc + pr_off + m * 16 * LDP + 32);
            }

            // ---- issue ka(kt+1) early; latency covered by l/O MFMAs below
            if (more) {
                kp += 4096;
#pragma unroll
                for (int i = 0; i < 4; ++i)
#pragma unroll
                    for (int h = 0; h < 2; ++h)
                        ka[i][h] = *(const bf16x8*)(kp + (i * 2 + h) * 512);
            }

            // ---- l += P @ ones ; O += P V(kt)
#pragma unroll
            for (int m = 0; m < 2; ++m) {
                f32x4 z = __builtin_amdgcn_mfma_f32_16x16x32_bf16(pa[m][0], onesf, lac[m], 0, 0, 0);
                lac[m] = __builtin_amdgcn_mfma_f32_16x16x32_bf16(pa[m][1], onesf, z, 0, 0, 0);
            }
#pragma unroll
            for (int dj = 0; dj < 4; ++dj)
#pragma unroll
                for (int m = 0; m < 2; ++m) {
                    f32x4 z = __builtin_amdgcn_mfma_f32_16x16x32_bf16(pa[m][0], vf[dj][0], O[m][dj], 0, 0, 0);
                    O[m][dj] = __builtin_amdgcn_mfma_f32_16x16x32_bf16(pa[m][1], vf[dj][1], z, 0, 0, 0);
                }

            if (more) {
                // ---- issue vf(kt+1); latency covered by QK + exp2 below
                vp += 4096;
#pragma unroll
                for (int dj = 0; dj < 4; ++dj)
#pragma unroll
                    for (int h = 0; h < 2; ++h)
                        vf[dj][h] = *(const bf16x8*)(vp + (dj * 2 + h) * 512);

                // ---- st(kt+1) = K Q^T (ka latency already covered)
                f32x4 st[2][4];
#pragma unroll
                for (int i = 0; i < 4; ++i)
#pragma unroll
                    for (int m = 0; m < 2; ++m) {
                        f32x4 z = __builtin_amdgcn_mfma_f32_16x16x32_bf16(ka[i][0], qt[m][0], zero, 0, 0, 0);
                        st[m][i] = __builtin_amdgcn_mfma_f32_16x16x32_bf16(ka[i][1], qt[m][1], z, 0, 0, 0);
                    }
                if (kt + 1 == nkt - 1) {
                    const int kb = (kt + 1) * 64;
#pragma unroll
                    for (int m = 0; m < 2; ++m)
#pragma unroll
                        for (int i = 0; i < 4; ++i)
#pragma unroll
                            for (int r = 0; r < 4; ++r)
                                if (kb + i * 16 + quad * 4 + r > q0 + m * 16 + l15)
                                    st[m][i][r] = -INFINITY;
                }
                // ---- p = exp2(s); pack; write P(kt+1) to other buffer
#pragma unroll
                for (int m = 0; m < 2; ++m)
#pragma unroll
                    for (int i = 0; i < 4; ++i) {
                        unsigned e0 = __float_as_uint(__builtin_amdgcn_exp2f(st[m][i][0])) + 0x8000u;
                        unsigned e1 = __float_as_uint(__builtin_amdgcn_exp2f(st[m][i][1])) + 0x8000u;
                        unsigned e2 = __float_as_uint(__builtin_amdgcn_exp2f(st[m][i][2])) + 0x8000u;
                        unsigned e3 = __float_as_uint(__builtin_amdgcn_exp2f(st[m][i][3])) + 0x8000u;
                        uint2 pk;
                        pk.x = __builtin_amdgcn_perm(e1, e0, 0x07060302);
                        pk.y = __builtin_amdgcn_perm(e3, e2, 0x07060302);
                        *(uint2*)(bn + pw_off + m * 16 * LDP + i * 16) = pk;
                    }
            }
        }
    }

    // ---- combine the 4 partial (O,l) via LDS (additive: no max was used)
    __syncthreads();   // all waves done with their P regions
    if (w > 0) {
        float* Ow = Cb + (w - 1) * 2560;
#pragma unroll
        for (int m = 0; m < 2; ++m) {
#pragma unroll
            for (int dj = 0; dj < 4; ++dj)
                *(f32x4*)&Ow[(m * 4 + dj) * 256 + lane * 4] = O[m][dj];
            *(f32x4*)&Ow[2048 + m * 256 + lane * 4] = lac[m];
        }
    }
    __syncthreads();
    if (w == 0) {
#pragma unroll
        for (int c = 0; c < 3; ++c) {
            const float* Ow = Cb + c * 2560;
#pragma unroll
            for (int m = 0; m < 2; ++m) {
#pragma unroll
                for (int dj = 0; dj < 4; ++dj)
                    O[m][dj] += *(const f32x4*)&Ow[(m * 4 + dj) * 256 + lane * 4];
                lac[m] += *(const f32x4*)&Ow[2048 + m * 256 + lane * 4];
            }
        }
        // epilogue: O / l -> Y [b][t][h*64+d] bf16
        const int b = bh / 12, hd = bh % 12;
#pragma unroll
        for (int m = 0; m < 2; ++m)
#pragma unroll
            for (int r = 0; r < 4; ++r) {
                float inv = 1.0f / lac[m][r];
                int t = q0 + 16 * m + quad * 4 + r;
                size_t base = ((size_t)(b * 4096 + t)) * 768 + hd * 64;
#pragma unroll
                for (int dj = 0; dj < 4; ++dj)
                    Y[base + dj * 16 + l15] = f2bf(O[m][dj][r] * inv);
            }
    }
}

// ---------------- launch ----------------
extern "C" void kernel_launch(void* const* d_in, const int* in_sizes, int n_in,
                              void* d_out, int out_size, void* d_ws, size_t ws_size,
                              hipStream_t stream) {
    (void)in_sizes; (void)n_in; (void)out_size; (void)ws_size;
    const float* x     = (const float*)d_in[0];
    const float* Wqkv  = (const float*)d_in[1];
    const float* bqkv  = (const float*)d_in[2];
    const float* Wproj = (const float*)d_in[3];
    const float* bproj = (const float*)d_in[4];
    float* out = (float*)d_out;

    char* ws = (char*)d_ws;
    size_t off = 0;
    auto alloc = [&](size_t bytes) -> void* {
        void* p = ws + off;
        off += (bytes + 255) & ~(size_t)255;
        return p;
    };
    unsigned short* xb     = (unsigned short*)alloc((size_t)8192 * 768 * 2);
    unsigned short* WqkvT  = (unsigned short*)alloc((size_t)2304 * 768 * 2);
    unsigned short* WprojT = (unsigned short*)alloc((size_t)768 * 768 * 2);
    unsigned short* QLb    = (unsigned short*)alloc((size_t)24 * 4096 * 64 * 2);
    unsigned short* KLb    = (unsigned short*)alloc((size_t)24 * 4096 * 64 * 2);
    unsigned short* VLb    = (unsigned short*)alloc((size_t)24 * 4096 * 64 * 2);
    unsigned short* Yb     = (unsigned short*)alloc((size_t)8192 * 768 * 2);

    k_convert<<<6144, 256, 0, stream>>>(x, xb, 8192 * 768 / 4);
    dim3 tb(32, 8);
    k_transpose<<<dim3(72, 24), tb, 0, stream>>>(Wqkv, WqkvT, 768, 2304);
    k_transpose<<<dim3(24, 24), tb, 0, stream>>>(Wproj, WprojT, 768, 768);
    k_gemm_qkv<<<dim3(64, 18), 256, 0, stream>>>(xb, WqkvT, bqkv, QLb, KLb, VLb);
    k_attn<<<dim3(3072), 256, 0, stream>>>(QLb, KLb, VLb, Yb);
    k_gemm_proj<<<dim3(64, 6), 256, 0, stream>>>(Yb, WprojT, bproj, out);
}